// Round 14
// baseline (69.937 us; speedup 1.0000x reference)
//
#include <hip/hip_runtime.h>
#include <hip/hip_bf16.h>
#include <stdint.h>

// Problem constants (B=8, C=512, H=W=32, N=4)
constexpr int BN = 32;     // B*N batch-heads
constexpr int Cn = 128;    // channels per head
constexpr int L  = 1024;   // H*W
constexpr int CC = 512;    // C
constexpr int BB = 8;      // B

typedef __bf16 bf16x8 __attribute__((ext_vector_type(8)));
typedef float  f32x4  __attribute__((ext_vector_type(4)));
typedef unsigned short u16x8 __attribute__((ext_vector_type(8)));

__device__ inline unsigned short f2bf(float f) {
    unsigned int x = __float_as_uint(f);
    x += 0x7fffu + ((x >> 16) & 1u);   // round-to-nearest-even
    return (unsigned short)(x >> 16);
}
__device__ inline __bf16 bfbits(unsigned short u) {
    union { unsigned short s; __bf16 b; } cv; cv.s = u; return cv.b;
}

// async global->LDS, 16B per lane (dest = wave-uniform base + lane*16)
__device__ inline void gl_lds16(const void* g, void* l) {
    typedef __attribute__((address_space(1))) const unsigned int GU;
    typedef __attribute__((address_space(3))) unsigned int LU;
    __builtin_amdgcn_global_load_lds((GU*)g, (LU*)l, 16, 0, 0);
}

// ---------------------------------------------------------------------------
// Kernel 0: M1 = w1^T*w2, M2 = w3^T*w4 (f32), stored hi/lo bf16, plain
// [mat][c][c'] rows.  scores = f^T*M1*s == Kt*Qt^T exactly.
// ---------------------------------------------------------------------------
__global__ __launch_bounds__(256)
void mkM_kernel(const float* __restrict__ w1, const float* __restrict__ w2,
                const float* __restrict__ w3, const float* __restrict__ w4,
                unsigned short* __restrict__ Mh, unsigned short* __restrict__ Ml)
{
    const int mb  = blockIdx.x;        // 0..15
    const int mat = mb >> 3;
    const int cq  = mb & 7;            // 16 c-rows each
    const int t   = threadIdx.x;
    const float* wa = mat ? w3 : w1;
    const float* wb = mat ? w4 : w2;
    const int c   = cq * 16 + (t & 15);
    const int cg2 = t >> 4;            // c' group of 8
    float acc[8];
    #pragma unroll
    for (int j = 0; j < 8; ++j) acc[j] = 0.f;
    for (int o = 0; o < 128; ++o) {
        float a = wa[o * 128 + c];
        #pragma unroll
        for (int j = 0; j < 8; ++j)
            acc[j] += a * wb[o * 128 + cg2 * 8 + j];
    }
    u16x8 hi, lo;
    #pragma unroll
    for (int j = 0; j < 8; ++j) {
        unsigned short h = f2bf(acc[j]);
        hi[j] = h;
        lo[j] = f2bf(acc[j] - __uint_as_float((unsigned)h << 16));
    }
    const int off = mat * 16384 + c * 128 + cg2 * 8;
    *(u16x8*)&Mh[off] = hi;
    *(u16x8*)&Ml[off] = lo;
}

// ---------------------------------------------------------------------------
// Kernel 1 (v6): prep with LINEAR input reads.
//   Y1T[m][c] = sum_c' M1[c][c'] s[c'][m] (3-pass split bf16), Y2T likewise.
// s-tile [128 c'][128 m] f32 staged UNCHANGED-layout via gl_lds16 (512B
// contiguous per c'-row — no transpose-pattern global reads).  Transpose
// happens at B-frag extraction (ds_read_b32 x8, <=4-way bank alias), hi/lo
// split in VALU.  M-frags resident.  yrep separate 64 KB; linear copy-out.
// grid = 256 = (bn32 x mo8 of 128 m); 512 thr = 8 waves = (mat2, cq4).
// LDS: ss 64 KB + yrep 64 KB = 128 KB -> 1 block/CU.
// ---------------------------------------------------------------------------
__global__ __launch_bounds__(512)
void prep_kernel(const float* __restrict__ second,
                 const unsigned short* __restrict__ Mh,
                 const unsigned short* __restrict__ Ml,
                 unsigned short* __restrict__ Y1, unsigned short* __restrict__ Y2)
{
    __shared__ float ss[128 * 128];              // 64 KB, [c'][m] as in global
    __shared__ unsigned short yrep[2][128 * 128];// 64 KB

    const int p  = blockIdx.x;
    const int mo = p & 7;              // 128-m block
    const int bn = p >> 3;

    const float* s = second + (size_t)bn * Cn * L + mo * 128;

    const int tid  = threadIdx.x;
    const int lane = tid & 63;
    const int wid  = tid >> 6;         // 0..7
    const int mat  = wid & 1;
    const int cq   = wid >> 1;         // 0..3 (32 out-c each)
    const int r16  = lane & 15;
    const int g    = lane >> 4;

    const unsigned short* MHm = Mh + mat * 16384;
    const unsigned short* MLm = Ml + mat * 16384;

    // ---- stage s-tile via gl_lds16: 8 issues x 8 KB, 512B per c'-row ----
    {
        const int row = tid >> 5;            // 0..15 per issue
        const int m4  = (tid & 31) * 4;
        #pragma unroll
        for (int i = 0; i < 8; ++i) {
            const int cr = i * 16 + row;
            gl_lds16(s + (size_t)cr * L + m4, &ss[cr * 128 + m4]);
        }
    }

    // ---- resident M frags: [og2][kk4] hi+lo = 64 VGPR ----
    bf16x8 mh[2][4], ml[2][4];
    #pragma unroll
    for (int og = 0; og < 2; ++og)
        #pragma unroll
        for (int kk = 0; kk < 4; ++kk) {
            int c  = cq * 32 + og * 16 + r16;
            int cp = kk * 32 + g * 8;
            mh[og][kk] = *(const bf16x8*)&MHm[c * 128 + cp];
            ml[og][kk] = *(const bf16x8*)&MLm[c * 128 + cp];
        }
    __syncthreads();

    // ---- compute 8 m-subtiles of 16; D-frags -> yrep (LDS scatter) ----
    #pragma unroll
    for (int ms = 0; ms < 8; ++ms) {
        const int m = ms * 16 + r16;         // m within tile
        // B-frags from ss (transpose read + hi/lo split)
        bf16x8 bh[4], bl[4];
        #pragma unroll
        for (int kk = 0; kk < 4; ++kk) {
            #pragma unroll
            for (int j = 0; j < 8; ++j) {
                float v = ss[(kk * 32 + g * 8 + j) * 128 + m];
                unsigned short h = f2bf(v);
                bh[kk][j] = bfbits(h);
                bl[kk][j] = bfbits(f2bf(v - __uint_as_float((unsigned)h << 16)));
            }
        }
        f32x4 acc[2];
        acc[0] = (f32x4){0.f, 0.f, 0.f, 0.f};
        acc[1] = (f32x4){0.f, 0.f, 0.f, 0.f};
        #pragma unroll
        for (int kk = 0; kk < 4; ++kk)
            #pragma unroll
            for (int og = 0; og < 2; ++og) {
                f32x4 a = acc[og];
                a = __builtin_amdgcn_mfma_f32_16x16x32_bf16(mh[og][kk], bh[kk], a, 0, 0, 0);
                a = __builtin_amdgcn_mfma_f32_16x16x32_bf16(ml[og][kk], bh[kk], a, 0, 0, 0);
                a = __builtin_amdgcn_mfma_f32_16x16x32_bf16(mh[og][kk], bl[kk], a, 0, 0, 0);
                acc[og] = a;
            }
        #pragma unroll
        for (int og = 0; og < 2; ++og) {
            const int c0 = cq * 32 + og * 16 + g * 4;
            f32x4 a = acc[og];
            ushort4 st;
            st.x = f2bf(a.x); st.y = f2bf(a.y);
            st.z = f2bf(a.z); st.w = f2bf(a.w);
            const int pos = (((c0 >> 3) ^ (m & 7)) << 3) | (c0 & 7);
            *(ushort4*)&yrep[mat][m * 128 + pos] = st;
        }
    }
    __syncthreads();

    // ---- coalesced copy-out: 16B x 512 threads, linear, 128 KB ----
    {
        unsigned short* Y1t = Y1 + (size_t)bn * (L * Cn) + mo * 16384;
        unsigned short* Y2t = Y2 + (size_t)bn * (L * Cn) + mo * 16384;
        #pragma unroll
        for (int i = 0; i < 4; ++i) {
            const int off = (i * 512 + tid) * 8;
            *(u16x8*)&Y1t[off] = *(const u16x8*)&yrep[0][off];
            *(u16x8*)&Y2t[off] = *(const u16x8*)&yrep[1][off];
        }
    }
}

// ---------------------------------------------------------------------------
// Kernel 2 (v6): swapped-operand MFMA attention, LINEAR f reads.
//   S[m][l] = sum_c Y1T[m][c] * f[c][l];  U likewise.  m in quarters (mh).
// Phase 1: f staged in two [64 c][256 l] f32 halves via gl_lds16 (1KB rows)
// into the Y-dbuf LDS region; B-frags (bf16-hi) extracted to registers
// (4 subtiles x 4 kk = 64 VGPR), then region handed to Y streaming.
// Phase 2: identical to R13 v5 (4 Y tiles, dbuf, 8 MFMA per qf/vf pair).
// grid = 512 = xcd8 x (bn4, lt4, mh4); LDS 64 KB; 2 blocks/CU.
// ---------------------------------------------------------------------------
__global__ __launch_bounds__(256, 2)
void attn_kernel(const float* __restrict__ first,
                 const unsigned short* __restrict__ Y1,
                 const unsigned short* __restrict__ Y2,
                 float* __restrict__ Dp, float* __restrict__ Rp)
{
    __shared__ char smem[2][32768];      // 64 KB, dual-purpose

    const int p   = blockIdx.x;          // 0..511
    const int xcd = p & 7;
    const int jj  = p >> 3;              // 0..63
    const int bn  = xcd * 4 + (jj & 3);  // all blocks of a bn on one XCD
    const int lt  = (jj >> 2) & 3;       // 0..3 (256-row l tile)
    const int mh  = jj >> 4;             // 0..3 (m quarter)

    const int tid  = threadIdx.x;
    const int lane = tid & 63;
    const int w    = tid >> 6;           // wave 0..3
    const int r16  = lane & 15;
    const int g    = lane >> 4;          // 0..3
    const int swz  = lane & 7;

    const size_t slab = (size_t)L * Cn;
    const float* f = first + (size_t)bn * slab;            // f32 [c][l]
    const unsigned short* Q = Y1 + (size_t)bn * slab;      // [m][c] swizzled
    const unsigned short* V = Y2 + (size_t)bn * slab;

    // ---- phase 1: two f32 halves, linear staging + register extraction ----
    bf16x8 bf[4][4];
    float* fsf = (float*)&smem[0][0];    // [64 c][256 l] per half
    #pragma unroll
    for (int half = 0; half < 2; ++half) {
        {
            const int row = tid >> 6;        // 0..3 per issue (1KB rows)
            const int l4  = (tid & 63) * 4;
            #pragma unroll
            for (int i = 0; i < 16; ++i) {
                const int c = half * 64 + i * 4 + row;
                gl_lds16(f + (size_t)c * L + lt * 256 + l4,
                         &fsf[(i * 4 + row) * 256 + l4]);
            }
        }
        __syncthreads();
        #pragma unroll
        for (int st = 0; st < 4; ++st)
            #pragma unroll
            for (int k2 = 0; k2 < 2; ++k2) {
                const int kk = half * 2 + k2;
                const int ll = (w * 4 + st) * 16 + r16;
                #pragma unroll
                for (int j = 0; j < 8; ++j) {
                    float v = fsf[(k2 * 32 + g * 8 + j) * 256 + ll];
                    bf[st][kk][j] = bfbits(f2bf(v));
                }
            }
        __syncthreads();
    }

    // ---- phase 2: stream 4 Y tiles (this mh quarter) ----
    auto STAGE = [&](int buf, int t) {
        const int m0 = mh * 256 + t * 64;
        const char* qs = (const char*)Q + (size_t)m0 * 256;
        const char* vs = (const char*)V + (size_t)m0 * 256;
        char* qd = &smem[buf][0];
        char* vd = &smem[buf][16384];
        #pragma unroll
        for (int it = 0; it < 4; ++it) {
            gl_lds16(qs + tid * 16 + it * 4096, qd + tid * 16 + it * 4096);
            gl_lds16(vs + tid * 16 + it * 4096, vd + tid * 16 + it * 4096);
        }
    };

    STAGE(0, 0);
    __syncthreads();                     // drains vmcnt

    float Dacc[4] = {0.f, 0.f, 0.f, 0.f};
    float Racc[4] = {0.f, 0.f, 0.f, 0.f};
    const f32x4 z = {0.f, 0.f, 0.f, 0.f};

    for (int t = 0; t < 4; ++t) {
        const int buf = t & 1;
        if (t < 3) STAGE(buf ^ 1, t + 1);     // loads in flight during compute
        const char* qb = &smem[buf][0];
        const char* vb = &smem[buf][16384];
        #pragma unroll
        for (int mg = 0; mg < 4; ++mg) {
            const int brow = mg * 16 + r16;             // brow&7 == swz
            const int rbase = brow * 256;
            bf16x8 qf[4], vf[4];
            #pragma unroll
            for (int kk = 0; kk < 4; ++kk) {
                int off = rbase + ((((kk << 2) + g) ^ swz) << 4);
                qf[kk] = *(const bf16x8*)(qb + off);
                vf[kk] = *(const bf16x8*)(vb + off);
            }
            #pragma unroll
            for (int st = 0; st < 4; ++st) {
                f32x4 s0 = z, u0 = z;
                #pragma unroll
                for (int kk = 0; kk < 4; ++kk) {
                    s0 = __builtin_amdgcn_mfma_f32_16x16x32_bf16(qf[kk], bf[st][kk], s0, 0, 0, 0);
                    u0 = __builtin_amdgcn_mfma_f32_16x16x32_bf16(vf[kk], bf[st][kk], u0, 0, 0, 0);
                }
                float e0 = __expf(s0.x - 8.f);
                float e1 = __expf(s0.y - 8.f);
                float e2 = __expf(s0.z - 8.f);
                float e3 = __expf(s0.w - 8.f);
                Dacc[st] += (e0 + e1) + (e2 + e3);
                Racc[st] += (e0 * u0.x + e1 * u0.y) + (e2 * u0.z + e3 * u0.w);
            }
        }
        __syncthreads();                 // next tile staged
    }

    // sum over the 4 row-groups (lanes 16 apart share col l = r16)
    #pragma unroll
    for (int st = 0; st < 4; ++st) {
        Dacc[st] += __shfl_xor(Dacc[st], 16);
        Racc[st] += __shfl_xor(Racc[st], 16);
        Dacc[st] += __shfl_xor(Dacc[st], 32);
        Racc[st] += __shfl_xor(Racc[st], 32);
    }
    if (g == 0) {
        #pragma unroll
        for (int st = 0; st < 4; ++st) {
            const int l = lt * 256 + (w * 4 + st) * 16 + r16;
            size_t idx = (size_t)mh * BN * L + (size_t)bn * L + l;
            Dp[idx] = Dacc[st];
            Rp[idx] = Racc[st];
        }
    }
}

// ---------------------------------------------------------------------------
// Kernel 3: res = sum_q R[q] / sum_q D[q].  32768 elems -> 128 blocks.
// ---------------------------------------------------------------------------
__global__ __launch_bounds__(256)
void combine_kernel(const float* __restrict__ Dp, const float* __restrict__ Rp,
                    float* __restrict__ res)
{
    int i = blockIdx.x * 256 + threadIdx.x;
    float d = Dp[i] + Dp[BN * L + i] + Dp[2 * BN * L + i] + Dp[3 * BN * L + i];
    float r = Rp[i] + Rp[BN * L + i] + Rp[2 * BN * L + i] + Rp[3 * BN * L + i];
    res[i] = r / d;
}

// ---------------------------------------------------------------------------
// Kernel 4: out[b][o][hw] = relu( sum_n w5[o][n] * res[b*4+n][hw] )
// ---------------------------------------------------------------------------
__global__ __launch_bounds__(256)
void out_kernel(const float* __restrict__ res, const float* __restrict__ w5,
                float* __restrict__ out)
{
    const int blk = blockIdx.x;
    const int o = blk & 511;
    const int b = blk >> 9;
    const float4 wv = *(const float4*)&w5[o * 4];

    const float* r0 = res + (size_t)(b * 4 + 0) * L;
    const float* r1 = res + (size_t)(b * 4 + 1) * L;
    const float* r2 = res + (size_t)(b * 4 + 2) * L;
    const float* r3 = res + (size_t)(b * 4 + 3) * L;

    const int hw = threadIdx.x * 4;
    float4 a0 = *(const float4*)&r0[hw];
    float4 a1 = *(const float4*)&r1[hw];
    float4 a2 = *(const float4*)&r2[hw];
    float4 a3 = *(const float4*)&r3[hw];

    float4 ov;
    ov.x = fmaxf(0.f, wv.x * a0.x + wv.y * a1.x + wv.z * a2.x + wv.w * a3.x);
    ov.y = fmaxf(0.f, wv.x * a0.y + wv.y * a1.y + wv.z * a2.y + wv.w * a3.y);
    ov.z = fmaxf(0.f, wv.x * a0.z + wv.y * a1.z + wv.z * a2.z + wv.w * a3.z);
    ov.w = fmaxf(0.f, wv.x * a0.w + wv.y * a1.w + wv.z * a2.w + wv.w * a3.w);

    *(float4*)&out[(size_t)blk * 1024 + hw] = ov;
}

// ---------------------------------------------------------------------------
extern "C" void kernel_launch(void* const* d_in, const int* in_sizes, int n_in,
                              void* d_out, int out_size, void* d_ws, size_t ws_size,
                              hipStream_t stream)
{
    const float* first  = (const float*)d_in[0];
    const float* second = (const float*)d_in[1];
    const float* w1 = (const float*)d_in[2];
    const float* w2 = (const float*)d_in[3];
    const float* w3 = (const float*)d_in[4];
    const float* w4 = (const float*)d_in[5];
    const float* w5 = (const float*)d_in[6];
    float* out = (float*)d_out;

    const size_t slabElems = (size_t)L * Cn;       // 131072
    const size_t arr = (size_t)BN * slabElems;     // 4,194,304 elems

    unsigned short* Y1 = (unsigned short*)d_ws;
    unsigned short* Y2 = Y1 + arr;
    unsigned short* Mh = Y2 + arr;
    unsigned short* Ml = Mh + 2 * 16384;
    float* Dp  = (float*)(Ml + 2 * 16384);
    float* Rp  = Dp + 4 * BN * L;
    float* res = Rp + 4 * BN * L;

    mkM_kernel<<<dim3(16), dim3(256), 0, stream>>>(w1, w2, w3, w4, Mh, Ml);
    prep_kernel<<<dim3(256), dim3(512), 0, stream>>>(second, Mh, Ml, Y1, Y2);
    attn_kernel<<<dim3(512), dim3(256), 0, stream>>>(first, Y1, Y2, Dp, Rp);
    combine_kernel<<<dim3(BN * L / 256), dim3(256), 0, stream>>>(Dp, Rp, res);
    out_kernel<<<dim3(BB * CC), dim3(256), 0, stream>>>(res, w5, out);
}

// Round 15
// 63.605 us; speedup vs baseline: 1.0996x; 1.0996x over previous
//
#include <hip/hip_runtime.h>
#include <hip/hip_bf16.h>
#include <stdint.h>

// Problem constants (B=8, C=512, H=W=32, N=4)
constexpr int BN = 32;     // B*N batch-heads
constexpr int Cn = 128;    // channels per head
constexpr int L  = 1024;   // H*W
constexpr int CC = 512;    // C
constexpr int BB = 8;      // B

typedef __bf16 bf16x8 __attribute__((ext_vector_type(8)));
typedef float  f32x4  __attribute__((ext_vector_type(4)));
typedef unsigned short u16x8 __attribute__((ext_vector_type(8)));

__device__ inline unsigned short f2bf(float f) {
    unsigned int x = __float_as_uint(f);
    x += 0x7fffu + ((x >> 16) & 1u);   // round-to-nearest-even
    return (unsigned short)(x >> 16);
}

// async global->LDS, 16B per lane (dest = wave-uniform base + lane*16)
__device__ inline void gl_lds16(const void* g, void* l) {
    typedef __attribute__((address_space(1))) const unsigned int GU;
    typedef __attribute__((address_space(3))) unsigned int LU;
    __builtin_amdgcn_global_load_lds((GU*)g, (LU*)l, 16, 0, 0);
}

// ---------------------------------------------------------------------------
// Kernel 0: M1 = w1^T*w2, M2 = w3^T*w4 (f32), stored hi/lo bf16, plain
// [mat][c][c'] rows.  scores = f^T*M1*s == Kt*Qt^T exactly.
// ---------------------------------------------------------------------------
__global__ __launch_bounds__(256)
void mkM_kernel(const float* __restrict__ w1, const float* __restrict__ w2,
                const float* __restrict__ w3, const float* __restrict__ w4,
                unsigned short* __restrict__ Mh, unsigned short* __restrict__ Ml)
{
    const int mb  = blockIdx.x;        // 0..15
    const int mat = mb >> 3;
    const int cq  = mb & 7;            // 16 c-rows each
    const int t   = threadIdx.x;
    const float* wa = mat ? w3 : w1;
    const float* wb = mat ? w4 : w2;
    const int c   = cq * 16 + (t & 15);
    const int cg2 = t >> 4;            // c' group of 8
    float acc[8];
    #pragma unroll
    for (int j = 0; j < 8; ++j) acc[j] = 0.f;
    for (int o = 0; o < 128; ++o) {
        float a = wa[o * 128 + c];
        #pragma unroll
        for (int j = 0; j < 8; ++j)
            acc[j] += a * wb[o * 128 + cg2 * 8 + j];
    }
    u16x8 hi, lo;
    #pragma unroll
    for (int j = 0; j < 8; ++j) {
        unsigned short h = f2bf(acc[j]);
        hi[j] = h;
        lo[j] = f2bf(acc[j] - __uint_as_float((unsigned)h << 16));
    }
    const int off = mat * 16384 + c * 128 + cg2 * 8;
    *(u16x8*)&Mh[off] = hi;
    *(u16x8*)&Ml[off] = lo;
}

// ---------------------------------------------------------------------------
// Kernel 1 (v7): prep, 2-pass split (Mh*sh + Ml*sh) — s_lo pass dropped
// (its contribution ~= the unavoidable bf16 storage rounding of Y).
//   Y1T[m][c] = sum_c' M1[c][c'] s[c'][m], Y2T likewise; Y bf16 in the attn
//   swizzle (16B chunk j of row m at j^(m&7)).
// grid = 512 = (bn32 x mt16 of 64 m); 512 thr = 8 waves = (mat2, cq4).
// LDS: sh 16 KB + yrep 32 KB = 48 KB -> 3 blocks/CU (was 2 in R13).
// ---------------------------------------------------------------------------
__global__ __launch_bounds__(512)
void prep_kernel(const float* __restrict__ second,
                 const unsigned short* __restrict__ Mh,
                 const unsigned short* __restrict__ Ml,
                 unsigned short* __restrict__ Y1, unsigned short* __restrict__ Y2)
{
    __shared__ unsigned short shs[64 * 128];     // 16 KB
    __shared__ unsigned short yrep[2][64 * 128]; // 32 KB

    const int p  = blockIdx.x;
    const int mt = p & 15;             // 64-row m tile
    const int bn = p >> 4;

    const float* s = second + (size_t)bn * Cn * L + mt * 64;

    const int tid  = threadIdx.x;
    const int lane = tid & 63;
    const int wid  = tid >> 6;         // 0..7
    const int mat  = wid & 1;
    const int cq   = wid >> 1;         // 0..3 (32 c each)
    const int r16  = lane & 15;
    const int g    = lane >> 4;

    const unsigned short* MHm = Mh + mat * 16384;
    const unsigned short* MLm = Ml + mat * 16384;

    // ---- resident M frags: [og2][kk4] hi+lo = 64 VGPR ----
    bf16x8 mh[2][4], ml[2][4];
    #pragma unroll
    for (int og = 0; og < 2; ++og)
        #pragma unroll
        for (int kk = 0; kk < 4; ++kk) {
            int c  = cq * 32 + og * 16 + r16;
            int cp = kk * 32 + g * 8;
            mh[og][kk] = *(const bf16x8*)&MHm[c * 128 + cp];
            ml[og][kk] = *(const bf16x8*)&MLm[c * 128 + cp];
        }

    // ---- stage sT tile (hi only): lane->m coalesced reads, 16B LDS writes ----
    {
        const int sm   = tid & 63;     // m within tile
        const int cblk = tid >> 6;     // 0..7 (16 c' each)
        #pragma unroll
        for (int h = 0; h < 2; ++h) {
            const int chunk = cblk * 2 + h;     // 0..15
            const int c0 = chunk * 8;
            float v[8];
            #pragma unroll
            for (int j = 0; j < 8; ++j)
                v[j] = s[(size_t)(c0 + j) * L + sm];
            u16x8 hi;
            #pragma unroll
            for (int j = 0; j < 8; ++j) hi[j] = f2bf(v[j]);
            const int off = sm * 128 + (chunk ^ (sm & 15)) * 8;
            *(u16x8*)&shs[off] = hi;
        }
    }
    __syncthreads();

    // ---- compute; D-frags -> yrep (LDS scatter) ----
    #pragma unroll
    for (int ms = 0; ms < 4; ++ms) {
        const int row = ms * 16 + r16;
        bf16x8 bh[4];
        #pragma unroll
        for (int kk = 0; kk < 4; ++kk) {
            const int slot = ((kk << 2) + g) ^ r16;   // row&15 == r16
            bh[kk] = *(const bf16x8*)&shs[row * 128 + slot * 8];
        }
        f32x4 acc[2];
        acc[0] = (f32x4){0.f, 0.f, 0.f, 0.f};
        acc[1] = (f32x4){0.f, 0.f, 0.f, 0.f};
        #pragma unroll
        for (int kk = 0; kk < 4; ++kk)
            #pragma unroll
            for (int og = 0; og < 2; ++og) {
                f32x4 a = acc[og];
                a = __builtin_amdgcn_mfma_f32_16x16x32_bf16(mh[og][kk], bh[kk], a, 0, 0, 0);
                a = __builtin_amdgcn_mfma_f32_16x16x32_bf16(ml[og][kk], bh[kk], a, 0, 0, 0);
                acc[og] = a;
            }
        const int m = ms * 16 + r16;                  // m within tile
        #pragma unroll
        for (int og = 0; og < 2; ++og) {
            const int c0 = cq * 32 + og * 16 + g * 4;
            f32x4 a = acc[og];
            ushort4 st;
            st.x = f2bf(a.x); st.y = f2bf(a.y);
            st.z = f2bf(a.z); st.w = f2bf(a.w);
            const int pos = (((c0 >> 3) ^ (m & 7)) << 3) | (c0 & 7);
            *(ushort4*)&yrep[mat][m * 128 + pos] = st;
        }
    }
    __syncthreads();

    // ---- coalesced copy-out: 16B x 512 threads, linear ----
    {
        unsigned short* Y1t = Y1 + (size_t)bn * (L * Cn) + mt * 8192;
        unsigned short* Y2t = Y2 + (size_t)bn * (L * Cn) + mt * 8192;
        #pragma unroll
        for (int i = 0; i < 2; ++i) {
            const int off = (i * 512 + tid) * 8;
            *(u16x8*)&Y1t[off] = *(const u16x8*)&yrep[0][off];
            *(u16x8*)&Y2t[off] = *(const u16x8*)&yrep[1][off];
        }
    }
}

// ---------------------------------------------------------------------------
// Kernel 2 (v5, reverted to R13): swapped-operand MFMA attention,
// 4 resident l-subtiles/wave, m in quarters (mh).
// ---------------------------------------------------------------------------
__global__ __launch_bounds__(256, 2)
void attn_kernel(const float* __restrict__ first,
                 const unsigned short* __restrict__ Y1,
                 const unsigned short* __restrict__ Y2,
                 float* __restrict__ Dp, float* __restrict__ Rp)
{
    __shared__ char smem[2][32768];      // 64 KB, dual-purpose

    const int p   = blockIdx.x;          // 0..511
    const int xcd = p & 7;
    const int jj  = p >> 3;              // 0..63
    const int bn  = xcd * 4 + (jj & 3);  // all blocks of a bn on one XCD
    const int lt  = (jj >> 2) & 3;       // 0..3 (256-row l tile)
    const int mh  = jj >> 4;             // 0..3 (m quarter)

    const int tid  = threadIdx.x;
    const int lane = tid & 63;
    const int w    = tid >> 6;           // wave 0..3
    const int r16  = lane & 15;
    const int g    = lane >> 4;          // 0..3
    const int swz  = lane & 7;

    const size_t slab = (size_t)L * Cn;
    const float* f = first + (size_t)bn * slab;            // f32 [c][l]
    const unsigned short* Q = Y1 + (size_t)bn * slab;      // [m][c] swizzled
    const unsigned short* V = Y2 + (size_t)bn * slab;

    // ---- phase 1: stage f l-slice (256 rows, hi bf16, &15-swizzled) ----
    {
        unsigned short* fs = (unsigned short*)&smem[0][0];
        const int sl   = tid & 63;       // l within 64-row group
        const int cblk = tid >> 6;       // 0..3 (32 c each)
        #pragma unroll
        for (int lq = 0; lq < 4; ++lq) {
            const int ll = lq * 64 + sl;               // l within tile (0..255)
            #pragma unroll
            for (int i = 0; i < 4; ++i) {
                const int chunk = cblk * 4 + i;        // 0..15
                const int c0 = chunk * 8;
                float v[8];
                #pragma unroll
                for (int j = 0; j < 8; ++j)
                    v[j] = f[(size_t)(c0 + j) * L + lt * 256 + ll];
                u16x8 hi;
                #pragma unroll
                for (int j = 0; j < 8; ++j) hi[j] = f2bf(v[j]);
                *(u16x8*)&fs[ll * 128 + (chunk ^ (ll & 15)) * 8] = hi;
            }
        }
    }
    __syncthreads();

    // ---- resident B-frags: 4 subtiles x 4 kk = 64 VGPR ----
    bf16x8 bf[4][4];
    {
        const unsigned short* fs = (const unsigned short*)&smem[0][0];
        #pragma unroll
        for (int st = 0; st < 4; ++st)
            #pragma unroll
            for (int kk = 0; kk < 4; ++kk) {
                const int row = (w * 4 + st) * 16 + r16;      // row&15 == r16
                const int slot = ((kk << 2) + g) ^ r16;
                bf[st][kk] = *(const bf16x8*)&fs[row * 128 + slot * 8];
            }
    }
    __syncthreads();   // all waves done reading fs; region now free for Y

    // ---- phase 2: stream 4 Y tiles (this mh quarter) ----
    auto STAGE = [&](int buf, int t) {
        const int m0 = mh * 256 + t * 64;
        const char* qs = (const char*)Q + (size_t)m0 * 256;
        const char* vs = (const char*)V + (size_t)m0 * 256;
        char* qd = &smem[buf][0];
        char* vd = &smem[buf][16384];
        #pragma unroll
        for (int it = 0; it < 4; ++it) {
            gl_lds16(qs + tid * 16 + it * 4096, qd + tid * 16 + it * 4096);
            gl_lds16(vs + tid * 16 + it * 4096, vd + tid * 16 + it * 4096);
        }
    };

    STAGE(0, 0);
    __syncthreads();                     // drains vmcnt

    float Dacc[4] = {0.f, 0.f, 0.f, 0.f};
    float Racc[4] = {0.f, 0.f, 0.f, 0.f};
    const f32x4 z = {0.f, 0.f, 0.f, 0.f};

    for (int t = 0; t < 4; ++t) {
        const int buf = t & 1;
        if (t < 3) STAGE(buf ^ 1, t + 1);     // loads in flight during compute
        const char* qb = &smem[buf][0];
        const char* vb = &smem[buf][16384];
        #pragma unroll
        for (int mg = 0; mg < 4; ++mg) {
            const int brow = mg * 16 + r16;             // brow&7 == swz
            const int rbase = brow * 256;
            bf16x8 qf[4], vf[4];
            #pragma unroll
            for (int kk = 0; kk < 4; ++kk) {
                int off = rbase + ((((kk << 2) + g) ^ swz) << 4);
                qf[kk] = *(const bf16x8*)(qb + off);
                vf[kk] = *(const bf16x8*)(vb + off);
            }
            #pragma unroll
            for (int st = 0; st < 4; ++st) {
                f32x4 s0 = z, u0 = z;
                #pragma unroll
                for (int kk = 0; kk < 4; ++kk) {
                    s0 = __builtin_amdgcn_mfma_f32_16x16x32_bf16(qf[kk], bf[st][kk], s0, 0, 0, 0);
                    u0 = __builtin_amdgcn_mfma_f32_16x16x32_bf16(vf[kk], bf[st][kk], u0, 0, 0, 0);
                }
                float e0 = __expf(s0.x - 8.f);
                float e1 = __expf(s0.y - 8.f);
                float e2 = __expf(s0.z - 8.f);
                float e3 = __expf(s0.w - 8.f);
                Dacc[st] += (e0 + e1) + (e2 + e3);
                Racc[st] += (e0 * u0.x + e1 * u0.y) + (e2 * u0.z + e3 * u0.w);
            }
        }
        __syncthreads();                 // next tile staged
    }

    // sum over the 4 row-groups (lanes 16 apart share col l = r16)
    #pragma unroll
    for (int st = 0; st < 4; ++st) {
        Dacc[st] += __shfl_xor(Dacc[st], 16);
        Racc[st] += __shfl_xor(Racc[st], 16);
        Dacc[st] += __shfl_xor(Dacc[st], 32);
        Racc[st] += __shfl_xor(Racc[st], 32);
    }
    if (g == 0) {
        #pragma unroll
        for (int st = 0; st < 4; ++st) {
            const int l = lt * 256 + (w * 4 + st) * 16 + r16;
            size_t idx = (size_t)mh * BN * L + (size_t)bn * L + l;
            Dp[idx] = Dacc[st];
            Rp[idx] = Racc[st];
        }
    }
}

// ---------------------------------------------------------------------------
// Kernel 3: res = sum_q R[q] / sum_q D[q].  32768 elems -> 128 blocks.
// ---------------------------------------------------------------------------
__global__ __launch_bounds__(256)
void combine_kernel(const float* __restrict__ Dp, const float* __restrict__ Rp,
                    float* __restrict__ res)
{
    int i = blockIdx.x * 256 + threadIdx.x;
    float d = Dp[i] + Dp[BN * L + i] + Dp[2 * BN * L + i] + Dp[3 * BN * L + i];
    float r = Rp[i] + Rp[BN * L + i] + Rp[2 * BN * L + i] + Rp[3 * BN * L + i];
    res[i] = r / d;
}

// ---------------------------------------------------------------------------
// Kernel 4: out[b][o][hw] = relu( sum_n w5[o][n] * res[b*4+n][hw] )
// ---------------------------------------------------------------------------
__global__ __launch_bounds__(256)
void out_kernel(const float* __restrict__ res, const float* __restrict__ w5,
                float* __restrict__ out)
{
    const int blk = blockIdx.x;
    const int o = blk & 511;
    const int b = blk >> 9;
    const float4 wv = *(const float4*)&w5[o * 4];

    const float* r0 = res + (size_t)(b * 4 + 0) * L;
    const float* r1 = res + (size_t)(b * 4 + 1) * L;
    const float* r2 = res + (size_t)(b * 4 + 2) * L;
    const float* r3 = res + (size_t)(b * 4 + 3) * L;

    const int hw = threadIdx.x * 4;
    float4 a0 = *(const float4*)&r0[hw];
    float4 a1 = *(const float4*)&r1[hw];
    float4 a2 = *(const float4*)&r2[hw];
    float4 a3 = *(const float4*)&r3[hw];

    float4 ov;
    ov.x = fmaxf(0.f, wv.x * a0.x + wv.y * a1.x + wv.z * a2.x + wv.w * a3.x);
    ov.y = fmaxf(0.f, wv.x * a0.y + wv.y * a1.y + wv.z * a2.y + wv.w * a3.y);
    ov.z = fmaxf(0.f, wv.x * a0.z + wv.y * a1.z + wv.z * a2.z + wv.w * a3.z);
    ov.w = fmaxf(0.f, wv.x * a0.w + wv.y * a1.w + wv.z * a2.w + wv.w * a3.w);

    *(float4*)&out[(size_t)blk * 1024 + hw] = ov;
}

// ---------------------------------------------------------------------------
extern "C" void kernel_launch(void* const* d_in, const int* in_sizes, int n_in,
                              void* d_out, int out_size, void* d_ws, size_t ws_size,
                              hipStream_t stream)
{
    const float* first  = (const float*)d_in[0];
    const float* second = (const float*)d_in[1];
    const float* w1 = (const float*)d_in[2];
    const float* w2 = (const float*)d_in[3];
    const float* w3 = (const float*)d_in[4];
    const float* w4 = (const float*)d_in[5];
    const float* w5 = (const float*)d_in[6];
    float* out = (float*)d_out;

    const size_t slabElems = (size_t)L * Cn;       // 131072
    const size_t arr = (size_t)BN * slabElems;     // 4,194,304 elems

    unsigned short* Y1 = (unsigned short*)d_ws;
    unsigned short* Y2 = Y1 + arr;
    unsigned short* Mh = Y2 + arr;
    unsigned short* Ml = Mh + 2 * 16384;
    float* Dp  = (float*)(Ml + 2 * 16384);
    float* Rp  = Dp + 4 * BN * L;
    float* res = Rp + 4 * BN * L;

    mkM_kernel<<<dim3(16), dim3(256), 0, stream>>>(w1, w2, w3, w4, Mh, Ml);
    prep_kernel<<<dim3(512), dim3(512), 0, stream>>>(second, Mh, Ml, Y1, Y2);
    attn_kernel<<<dim3(512), dim3(256), 0, stream>>>(first, Y1, Y2, Dp, Rp);
    combine_kernel<<<dim3(BN * L / 256), dim3(256), 0, stream>>>(Dp, Rp, res);
    out_kernel<<<dim3(BB * CC), dim3(256), 0, stream>>>(res, w5, out);
}